// Round 6
// baseline (2622.644 us; speedup 1.0000x reference)
//
#include <hip/hip_runtime.h>
#include <cmath>

#define HH 128
#define WW 128
#define HWSZ (HH * WW)

static __device__ __forceinline__ int imin(int a, int b) { return a < b ? a : b; }
static __device__ __forceinline__ int imax(int a, int b) { return a > b ? a : b; }

// ---------------------------------------------------------------------------
// Weight transpose: w[cout][cin][3][3] -> wt[cin_pad][9][128] (zero padded)
// ---------------------------------------------------------------------------
__global__ void wtrans_kernel(const float* __restrict__ w, float* __restrict__ wt,
                              int cout, int cin, int cin_pad) {
  int idx = blockIdx.x * 256 + threadIdx.x;
  int total = cin_pad * 9 * 128;
  if (idx >= total) return;
  int co = idx & 127;
  int t  = (idx >> 7) % 9;
  int ci = idx / (9 * 128);
  float v = 0.f;
  if (co < cout && ci < cin) v = w[((size_t)co * cin + ci) * 9 + t];
  wt[idx] = v;
}

// ---------------------------------------------------------------------------
// Fused 3x3 conv, 2-phase pipelined (T3-min + T14 reg-staged):
// issue loads(ch+1) -> einsum(ch) -> commit LDS(ch+1) -> barrier.
// Block: 256 thr = 64px x 128co; per-thread 4co x 8px. cin chunks of 4.
// wt layout: [cin_pad][9][128]. XCD-contiguous block swizzle (1024 blocks).
// ---------------------------------------------------------------------------
__global__ __launch_bounds__(256) void conv3x3_kernel(
    const float* __restrict__ in, const float* __restrict__ wt,
    const float* __restrict__ bias, float* __restrict__ out,
    int cin, int nch, int cout, int lrelu) {
  __shared__ __align__(16) float s_in[2][4 * 3 * 68];   // [buf][cl][row][68]
  __shared__ __align__(16) float s_w[2][4 * 9 * 128];   // [buf][cl][tap][co]

  const int tid = threadIdx.x;
  int bid = blockIdx.x;                    // 1024 blocks, 1024%8==0
  bid = (bid & 7) * 128 + (bid >> 3);      // XCD-contiguous chunks of 128
  const int x0 = (bid & 1) * 64;
  const int y  = (bid >> 1) & 127;
  const int b  = bid >> 8;
  const int px0 = (tid & 7) * 8;           // 8 px groups x 8 px
  const int co0 = (tid >> 3) * 4;          // 32 co groups x 4 co

  float acc[4][8];
#pragma unroll
  for (int i = 0; i < 4; ++i)
#pragma unroll
    for (int j = 0; j < 8; ++j) acc[i][j] = 0.f;

  float st_w[18];   // 4*9*128 = 4608 = 18*256
  float st_in[4];   // 4*3*66  = 792 <= 4*256

  // ---- stage issue: global -> regs (loads fly while einsum runs)
  auto issue = [&](int ch) {
    const float* wp = wt + (size_t)ch * 4608;
#pragma unroll
    for (int k = 0; k < 18; ++k) st_w[k] = wp[tid + k * 256];
    const int c0 = ch * 4;
#pragma unroll
    for (int k = 0; k < 4; ++k) {
      const int idx = tid + k * 256;
      float v = 0.f;
      if (idx < 792) {
        const int cl  = idx / 198;          // 3*66
        const int rem = idx - cl * 198;
        const int r   = rem / 66;
        const int col = rem - r * 66;
        const int c  = c0 + cl;
        const int gy = y + r - 1;
        const int gx = x0 + col - 1;
        if (c < cin && (unsigned)gy < (unsigned)HH && (unsigned)gx < (unsigned)WW)
          v = in[(((size_t)b * cin + c) * HH + gy) * WW + gx];
      }
      st_in[k] = v;
    }
  };
  // ---- stage commit: regs -> LDS
  auto commit = [&](int buf) {
#pragma unroll
    for (int k = 0; k < 18; ++k) s_w[buf][tid + k * 256] = st_w[k];
#pragma unroll
    for (int k = 0; k < 4; ++k) {
      const int idx = tid + k * 256;
      if (idx < 792) {
        const int cl  = idx / 198;
        const int rem = idx - cl * 198;
        const int r   = rem / 66;
        const int col = rem - r * 66;
        s_in[buf][(cl * 3 + r) * 68 + col] = st_in[k];
      }
    }
  };

  issue(0);
  commit(0);
  __syncthreads();

  for (int ch = 0; ch < nch; ++ch) {
    const int cur = ch & 1;
    const bool more = (ch + 1 < nch);
    if (more) issue(ch + 1);
    // ---- einsum on buffer cur: 36 rank-1 steps x 32 FMA
#pragma unroll
    for (int cl = 0; cl < 4; ++cl) {
#pragma unroll
      for (int di = 0; di < 3; ++di) {
        const float* rp = &s_in[cur][(cl * 3 + di) * 68 + px0];
        float4 a0 = *(const float4*)rp;
        float4 a1 = *(const float4*)(rp + 4);
        float2 a2 = *(const float2*)(rp + 8);
        float in10[10] = {a0.x, a0.y, a0.z, a0.w, a1.x, a1.y, a1.z, a1.w, a2.x, a2.y};
#pragma unroll
        for (int dj = 0; dj < 3; ++dj) {
          float4 wv = *(const float4*)&s_w[cur][(cl * 9 + di * 3 + dj) * 128 + co0];
          float wr[4] = {wv.x, wv.y, wv.z, wv.w};
#pragma unroll
          for (int cc = 0; cc < 4; ++cc)
#pragma unroll
            for (int p = 0; p < 8; ++p)
              acc[cc][p] += wr[cc] * in10[p + dj];
        }
      }
    }
    if (more) commit(cur ^ 1);
    __syncthreads();
  }

  // ---- epilogue
#pragma unroll
  for (int cc = 0; cc < 4; ++cc) {
    const int co = co0 + cc;
    if (co < cout) {
      const float bv = bias[co];
      float v[8];
#pragma unroll
      for (int p = 0; p < 8; ++p) {
        float t = acc[cc][p] + bv;
        if (lrelu) t = (t >= 0.f) ? t : 0.1f * t;
        v[p] = t;
      }
      float* op = out + (((size_t)b * cout + co) * HH + y) * WW + x0 + px0;
      *(float4*)op       = make_float4(v[0], v[1], v[2], v[3]);
      *(float4*)(op + 4) = make_float4(v[4], v[5], v[6], v[7]);
    }
  }
}

// ---------------------------------------------------------------------------
// Modulated deformable conv 3x3, 2-phase pipelined.
// Block: 256 thr = 64px x 128co; per-thread 4co x 8px. cin chunks of 2.
// Bilinear gather issued into regs ahead of einsum; combined at commit.
// wt layout: [cin][9][128].
// ---------------------------------------------------------------------------
__global__ __launch_bounds__(256) void deform_kernel(
    const float* __restrict__ x, const float* __restrict__ head,
    const float* __restrict__ flow, const float* __restrict__ wt,
    const float* __restrict__ bias, float* __restrict__ out) {
  __shared__ __align__(16) float s_s[2][2 * 9 * 64];    // [buf][cl][tap][px]
  __shared__ __align__(16) float s_w[2][2 * 9 * 128];   // [buf][cl][tap][co]

  const int tid = threadIdx.x;
  int bid = blockIdx.x;                    // 1024 blocks
  bid = (bid & 7) * 128 + (bid >> 3);      // XCD-contiguous
  const int x0 = (bid & 1) * 64;
  const int y  = (bid >> 1) & 127;
  const int b  = bid >> 8;
  const int px0 = (tid & 7) * 8;           // 8 px groups x 8 px
  const int co0 = (tid >> 3) * 4;          // 32 co groups x 4 co

  // ---- per-(tap,px) pair precompute: 576 pairs over 256 threads (2-3 each)
  int   p_i00[3], p_i01[3], p_i10[3], p_i11[3], p_sb[3];
  float p_w00[3], p_w01[3], p_w10[3], p_w11[3];
#pragma unroll
  for (int i = 0; i < 3; ++i) {
    const int pid = tid + i * 256;
    const bool act = (i < 2) || (tid < 64);
    p_w00[i] = p_w01[i] = p_w10[i] = p_w11[i] = 0.f;
    p_i00[i] = p_i01[i] = p_i10[i] = p_i11[i] = 0;
    p_sb[i] = 0;
    if (act) {
      const int k  = pid >> 6;             // 0..8
      const int px = pid & 63;
      const int gx = x0 + px;
      const size_t pix = (size_t)y * WW + gx;
      const float* hb = head + (size_t)b * 27 * HWSZ;
      const float hy = hb[(size_t)(2 * k) * HWSZ + pix];
      const float hx = hb[(size_t)(2 * k + 1) * HWSZ + pix];
      const float hm = hb[(size_t)(18 + k) * HWSZ + pix];
      const float* fb = flow + (size_t)b * 2 * HWSZ;
      const float fly = fb[HWSZ + pix];    // flow[:,1] -> dy
      const float flx = fb[pix];           // flow[:,0] -> dx
      const float dy = 3.f * tanhf(hy) + fly;
      const float dx = 3.f * tanhf(hx) + flx;
      const float py  = (float)(y - 1 + (k / 3)) + dy;
      const float pxx = (float)(gx - 1 + (k % 3)) + dx;
      const float y0f = floorf(py), x0f = floorf(pxx);
      const float fy = py - y0f, fx = pxx - x0f;
      const int iy0 = (int)y0f, ix0 = (int)x0f;
      const int iy1 = iy0 + 1,  ix1 = ix0 + 1;
      const float m = 1.f / (1.f + expf(-hm));   // sigmoid mask folded in
      const float vy0 = (iy0 >= 0 && iy0 < HH) ? m : 0.f;
      const float vy1 = (iy1 >= 0 && iy1 < HH) ? m : 0.f;
      const float vx0 = (ix0 >= 0 && ix0 < WW) ? 1.f : 0.f;
      const float vx1 = (ix1 >= 0 && ix1 < WW) ? 1.f : 0.f;
      p_w00[i] = (1.f - fy) * (1.f - fx) * vy0 * vx0;
      p_w01[i] = (1.f - fy) * fx * vy0 * vx1;
      p_w10[i] = fy * (1.f - fx) * vy1 * vx0;
      p_w11[i] = fy * fx * vy1 * vx1;
      const int cy0 = imin(imax(iy0, 0), HH - 1);
      const int cy1 = imin(imax(iy1, 0), HH - 1);
      const int cx0 = imin(imax(ix0, 0), WW - 1);
      const int cx1 = imin(imax(ix1, 0), WW - 1);
      p_i00[i] = cy0 * WW + cx0;
      p_i01[i] = cy0 * WW + cx1;
      p_i10[i] = cy1 * WW + cx0;
      p_i11[i] = cy1 * WW + cx1;
      p_sb[i] = k * 64 + px;
    }
  }

  float acc[4][8];
#pragma unroll
  for (int i = 0; i < 4; ++i)
#pragma unroll
    for (int j = 0; j < 8; ++j) acc[i][j] = 0.f;

  float st_w[9];                 // 2*9*128 = 2304 = 9*256
  float g00[3][2], g01[3][2], g10[3][2], g11[3][2];   // gather regs

  auto issue = [&](int ch) {
    const float* wp = wt + (size_t)ch * 2304;
#pragma unroll
    for (int k = 0; k < 9; ++k) st_w[k] = wp[tid + k * 256];
    const float* xb = x + ((size_t)b * 128 + ch * 2) * HWSZ;
#pragma unroll
    for (int i = 0; i < 3; ++i) {
      if (i < 2 || tid < 64) {
#pragma unroll
        for (int cl = 0; cl < 2; ++cl) {
          const float* xp = xb + (size_t)cl * HWSZ;
          g00[i][cl] = xp[p_i00[i]];
          g01[i][cl] = xp[p_i01[i]];
          g10[i][cl] = xp[p_i10[i]];
          g11[i][cl] = xp[p_i11[i]];
        }
      }
    }
  };
  auto commit = [&](int buf) {
#pragma unroll
    for (int k = 0; k < 9; ++k) s_w[buf][tid + k * 256] = st_w[k];
#pragma unroll
    for (int i = 0; i < 3; ++i) {
      if (i < 2 || tid < 64) {
#pragma unroll
        for (int cl = 0; cl < 2; ++cl) {
          s_s[buf][cl * 576 + p_sb[i]] =
              p_w00[i] * g00[i][cl] + p_w01[i] * g01[i][cl] +
              p_w10[i] * g10[i][cl] + p_w11[i] * g11[i][cl];
        }
      }
    }
  };

  issue(0);
  commit(0);
  __syncthreads();

  for (int ch = 0; ch < 64; ++ch) {
    const int cur = ch & 1;
    const bool more = (ch + 1 < 64);
    if (more) issue(ch + 1);
    // ---- einsum on buffer cur: 18 rank-1 steps x 32 FMA
#pragma unroll
    for (int cl = 0; cl < 2; ++cl) {
#pragma unroll
      for (int k = 0; k < 9; ++k) {
        const int rk = cl * 9 + k;
        float4 wv  = *(const float4*)&s_w[cur][rk * 128 + co0];
        float4 sa  = *(const float4*)&s_s[cur][rk * 64 + px0];
        float4 sb4 = *(const float4*)&s_s[cur][rk * 64 + px0 + 4];
        float wr[4] = {wv.x, wv.y, wv.z, wv.w};
        float sv[8] = {sa.x, sa.y, sa.z, sa.w, sb4.x, sb4.y, sb4.z, sb4.w};
#pragma unroll
        for (int cc = 0; cc < 4; ++cc)
#pragma unroll
          for (int p = 0; p < 8; ++p)
            acc[cc][p] += wr[cc] * sv[p];
      }
    }
    if (more) commit(cur ^ 1);
    __syncthreads();
  }

  // ---- epilogue
#pragma unroll
  for (int cc = 0; cc < 4; ++cc) {
    const int co = co0 + cc;
    const float bv = bias[co];
    float v[8];
#pragma unroll
    for (int p = 0; p < 8; ++p) v[p] = acc[cc][p] + bv;
    float* op = out + (((size_t)b * 128 + co) * HH + y) * WW + x0 + px0;
    *(float4*)op       = make_float4(v[0], v[1], v[2], v[3]);
    *(float4*)(op + 4) = make_float4(v[4], v[5], v[6], v[7]);
  }
}

// ---------------------------------------------------------------------------
// Launch
// ---------------------------------------------------------------------------
extern "C" void kernel_launch(void* const* d_in, const int* in_sizes, int n_in,
                              void* d_out, int out_size, void* d_ws, size_t ws_size,
                              hipStream_t stream) {
  const float* x    = (const float*)d_in[0];
  const float* cond = (const float*)d_in[1];
  const float* flow = (const float*)d_in[2];
  const float* w1 = (const float*)d_in[3];
  const float* b1 = (const float*)d_in[4];
  const float* w2 = (const float*)d_in[5];
  const float* b2 = (const float*)d_in[6];
  const float* w3 = (const float*)d_in[7];
  const float* b3 = (const float*)d_in[8];
  const float* w4 = (const float*)d_in[9];
  const float* b4 = (const float*)d_in[10];
  const float* wd = (const float*)d_in[11];
  const float* bd = (const float*)d_in[12];
  float* out = (float*)d_out;
  float* ws  = (float*)d_ws;

  // workspace layout (floats); head aliases f2 (dead after conv3)
  float* f1    = ws;                       // 8388608
  float* f2    = f1 + 8388608;             // 8388608
  float* headb = f2;                       // 1769472 (aliases f2)
  float* wt1   = f2 + 8388608;             // 264*9*128 = 304128
  float* wt2   = wt1 + 304128;             // 147456
  float* wt3   = wt2 + 147456;             // 147456
  float* wt4   = wt3 + 147456;             // 147456 (cout 27 zero-padded)
  float* wtd   = wt4 + 147456;             // 147456

  dim3 blk256(256);

  // weight transposes (tiny)
  {
    int t1 = 264 * 9 * 128;
    hipLaunchKernelGGL(wtrans_kernel, dim3((t1 + 255) / 256), blk256, 0, stream, w1, wt1, 128, 261, 264);
    int t2 = 128 * 9 * 128;
    hipLaunchKernelGGL(wtrans_kernel, dim3((t2 + 255) / 256), blk256, 0, stream, w2, wt2, 128, 128, 128);
    hipLaunchKernelGGL(wtrans_kernel, dim3((t2 + 255) / 256), blk256, 0, stream, w3, wt3, 128, 128, 128);
    hipLaunchKernelGGL(wtrans_kernel, dim3((t2 + 255) / 256), blk256, 0, stream, w4, wt4, 27, 128, 128);
    hipLaunchKernelGGL(wtrans_kernel, dim3((t2 + 255) / 256), blk256, 0, stream, wd, wtd, 128, 128, 128);
  }

  dim3 cgrid(1024);   // 2 x-halves * 128 y * 4 b, XCD-swizzled in-kernel
  // conv1: cond(261) -> f1, lrelu (nch = 264/4 = 66)
  hipLaunchKernelGGL(conv3x3_kernel, cgrid, blk256, 0, stream, cond, wt1, b1, f1, 261, 66, 128, 1);
  // conv2: f1 -> f2, lrelu
  hipLaunchKernelGGL(conv3x3_kernel, cgrid, blk256, 0, stream, f1, wt2, b2, f2, 128, 32, 128, 1);
  // conv3: f2 -> f1, lrelu
  hipLaunchKernelGGL(conv3x3_kernel, cgrid, blk256, 0, stream, f2, wt3, b3, f1, 128, 32, 128, 1);
  // conv4 (head): f1 -> headb (aliases f2, safe), no activation
  hipLaunchKernelGGL(conv3x3_kernel, cgrid, blk256, 0, stream, f1, wt4, b4, headb, 128, 32, 27, 0);
  // deformable conv
  hipLaunchKernelGGL(deform_kernel, cgrid, blk256, 0, stream, x, headb, flow, wtd, bd, out);
}

// Round 9
// 1039.312 us; speedup vs baseline: 2.5234x; 2.5234x over previous
//
#include <hip/hip_runtime.h>
#include <cmath>

#define HH 128
#define WW 128
#define HWSZ (HH * WW)

typedef __attribute__((ext_vector_type(8))) short short8v;
typedef __attribute__((ext_vector_type(4))) float f32x4;

static __device__ __forceinline__ int imin(int a, int b) { return a < b ? a : b; }
static __device__ __forceinline__ int imax(int a, int b) { return a > b ? a : b; }

// Split fp32 -> bf16 hi + bf16 lo (RNE both), f ~= hi + lo with residual ~2^-17|f|
static __device__ __forceinline__ void bf16split(float f, short& hi, short& lo) {
  unsigned u = __float_as_uint(f);
  unsigned rh = u + 0x7fffu + ((u >> 16) & 1u);
  hi = (short)(rh >> 16);
  float fh = __uint_as_float((rh >> 16) << 16);
  float res = f - fh;
  unsigned v = __float_as_uint(res);
  unsigned rl = v + 0x7fffu + ((v >> 16) & 1u);
  lo = (short)(rl >> 16);
}

// ---------------------------------------------------------------------------
// MFMA weight prepack: w[cout][cin_real][3][3] -> per-lane B-fragments.
// K order: ks = cinblk*9 + tap; within a K-step of 32: k = (lane>>4)*8 + j = cin_local.
// whi/wlo[((ct*nks + ks)*64 + lane)*8 + j] = bf16hi/lo(w[ct*16+(lane&15)][cin][tap])
// ---------------------------------------------------------------------------
__global__ void wpack_kernel(const float* __restrict__ w, short* __restrict__ whi,
                             short* __restrict__ wlo, int nct, int nks,
                             int cin_real, int cout) {
  int idx = blockIdx.x * 256 + threadIdx.x;
  int total = nct * nks * 512;
  if (idx >= total) return;
  int j    = idx & 7;
  int lane = (idx >> 3) & 63;
  int t2   = idx >> 9;
  int ks   = t2 % nks;
  int ct   = t2 / nks;
  int cinb = ks / 9, tap = ks % 9;
  int cin = cinb * 32 + (lane >> 4) * 8 + j;
  int co  = ct * 16 + (lane & 15);
  float v = 0.f;
  if (co < cout && cin < cin_real) v = w[((size_t)co * cin_real + cin) * 9 + tap];
  short hi, lo;
  bf16split(v, hi, lo);
  whi[idx] = hi;
  wlo[idx] = lo;
}

// ---------------------------------------------------------------------------
// 3x3 conv via MFMA bf16 3-product split (AhBh + AhBl + AlBh).
// Block 256 thr = 4 waves; wave w computes D[px-tile w (16 px)][NCT*16 co].
// Per cin-chunk of 32: stage input rows y-1..y+1 transposed to
// s_a[row][hi/lo][66 px][40-pad cin] (bf16), then 9 taps = 9 K-steps of 32.
// A-frag: lane(g,m): s_a[r][h][wv*16+m+c][g*8..+7] (16B, bank-balanced).
// B-frag: prepacked global, 16B/lane. D: col=lane&15 (co), row=(lane>>4)*4+reg (px).
// ---------------------------------------------------------------------------
template <int NCT>
__global__ __launch_bounds__(256, 2) void conv_mfma_kernel(
    const float* __restrict__ in, const short* __restrict__ wh,
    const short* __restrict__ wl, const float* __restrict__ bias,
    float* __restrict__ out, int cin_real, int CB, int cout, int lrelu) {
  __shared__ __align__(16) short s_a[3][2][66][40];

  const int tid = threadIdx.x;
  int bid = blockIdx.x;                  // 1024 blocks, 1024%8==0
  bid = (bid & 7) * 128 + (bid >> 3);    // XCD-contiguous chunks of 128
  const int x0 = (bid & 1) * 64;
  const int y  = (bid >> 1) & 127;
  const int b  = bid >> 8;
  const int lane = tid & 63;
  const int wv = tid >> 6;               // px-tile 0..3
  const int m = lane & 15;
  const int g = lane >> 4;
  const int NKS = CB * 9;

  f32x4 acc[NCT];
#pragma unroll
  for (int ct = 0; ct < NCT; ++ct) acc[ct] = (f32x4){0.f, 0.f, 0.f, 0.f};

  for (int cb = 0; cb < CB; ++cb) {
    // ---- stage: 32 cin x 3 rows x 66 px, fp32 -> bf16 hi/lo, transposed
    for (int i = tid; i < 3 * 32 * 66; i += 256) {
      int px = i % 66;
      int q  = i / 66;
      int ci = q & 31;
      int row = q >> 5;
      int c  = cb * 32 + ci;
      int gy = y + row - 1;
      int gx = x0 + px - 1;
      float v = 0.f;
      if (c < cin_real && (unsigned)gy < (unsigned)HH && (unsigned)gx < (unsigned)WW)
        v = in[((size_t)(b * cin_real + c) * HH + gy) * WW + gx];
      short hi, lo;
      bf16split(v, hi, lo);
      s_a[row][0][px][ci] = hi;
      s_a[row][1][px][ci] = lo;
    }
    __syncthreads();
    // ---- 9 taps = 9 K-steps of 32 cins
#pragma unroll
    for (int tap = 0; tap < 9; ++tap) {
      const int r = tap / 3;
      const int c = tap - r * 3;
      const int pxi = wv * 16 + m + c;   // <= 65
      short8v ah = *(const short8v*)&s_a[r][0][pxi][g * 8];
      short8v al = *(const short8v*)&s_a[r][1][pxi][g * 8];
      const int ks = cb * 9 + tap;
#pragma unroll
      for (int ct = 0; ct < NCT; ++ct) {
        const size_t off = ((size_t)(ct * NKS + ks) * 64 + lane) * 8;
        short8v bh = *(const short8v*)(wh + off);
        short8v bl = *(const short8v*)(wl + off);
        acc[ct] = __builtin_amdgcn_mfma_f32_16x16x32_bf16(ah, bh, acc[ct], 0, 0, 0);
        acc[ct] = __builtin_amdgcn_mfma_f32_16x16x32_bf16(ah, bl, acc[ct], 0, 0, 0);
        acc[ct] = __builtin_amdgcn_mfma_f32_16x16x32_bf16(al, bh, acc[ct], 0, 0, 0);
      }
    }
    __syncthreads();   // protect s_a before next chunk's stage
  }

  // ---- epilogue: D col = lane&15 (co), rows = (lane>>4)*4 + reg (px, contiguous)
  const int co_l = lane & 15;
  const int pxw  = wv * 16 + (lane >> 4) * 4;
#pragma unroll
  for (int ct = 0; ct < NCT; ++ct) {
    const int co = ct * 16 + co_l;
    if (co < cout) {
      const float bv = bias[co];
      float v0 = acc[ct][0] + bv;
      float v1 = acc[ct][1] + bv;
      float v2 = acc[ct][2] + bv;
      float v3 = acc[ct][3] + bv;
      if (lrelu) {
        v0 = (v0 >= 0.f) ? v0 : 0.1f * v0;
        v1 = (v1 >= 0.f) ? v1 : 0.1f * v1;
        v2 = (v2 >= 0.f) ? v2 : 0.1f * v2;
        v3 = (v3 >= 0.f) ? v3 : 0.1f * v3;
      }
      float* op = out + ((size_t)(b * cout + co) * HH + y) * WW + x0 + pxw;
      *(float4*)op = make_float4(v0, v1, v2, v3);
    }
  }
}

// ---------------------------------------------------------------------------
// Modulated deformable conv 3x3 via MFMA bf16 3-product split. LDS-free.
// Block 256 = 4 waves; wave wv owns 16 px (lane&15 = px within tile, matching
// the A-operand row convention). Each lane precomputes its pixel's 9 tap
// bilinear params (statically indexed arrays -> registers), then per K-step
// (cinblk of 32 x tap) gathers 8 cins x 4 corners, splits, and runs
// 8 ct x 3 MFMA. B prepacked by wpack_kernel (same layout as convs).
// ---------------------------------------------------------------------------
__global__ __launch_bounds__(256, 2) void deform_mfma_kernel(
    const float* __restrict__ x, const float* __restrict__ head,
    const float* __restrict__ flow, const short* __restrict__ wh,
    const short* __restrict__ wl, const float* __restrict__ bias,
    float* __restrict__ out) {
  const int tid = threadIdx.x;
  int bid = blockIdx.x;                  // 1024 blocks
  bid = (bid & 7) * 128 + (bid >> 3);    // XCD-contiguous
  const int x0 = (bid & 1) * 64;
  const int y  = (bid >> 1) & 127;
  const int b  = bid >> 8;
  const int lane = tid & 63;
  const int wv = tid >> 6;
  const int m = lane & 15;
  const int g = lane >> 4;
  const int gx = x0 + wv * 16 + m;       // this lane's pixel (A row = lane&15)

  // ---- per-tap bilinear params for pixel (y, gx)
  int   i00[9], i01[9], i10[9], i11[9];
  float w00[9], w01[9], w10[9], w11[9];
  {
    const float* hb = head + (size_t)b * 27 * HWSZ;
    const size_t pix = (size_t)y * WW + gx;
    const float fly = flow[((size_t)b * 2 + 1) * HWSZ + pix];   // flow[:,1] -> dy
    const float flx = flow[((size_t)b * 2 + 0) * HWSZ + pix];   // flow[:,0] -> dx
#pragma unroll
    for (int k = 0; k < 9; ++k) {
      const float hy = hb[(size_t)(2 * k) * HWSZ + pix];
      const float hx = hb[(size_t)(2 * k + 1) * HWSZ + pix];
      const float hm = hb[(size_t)(18 + k) * HWSZ + pix];
      const float dy = 3.f * tanhf(hy) + fly;
      const float dx = 3.f * tanhf(hx) + flx;
      const float py  = (float)(y - 1 + (k / 3)) + dy;
      const float pxx = (float)(gx - 1 + (k % 3)) + dx;
      const float y0f = floorf(py), x0f = floorf(pxx);
      const float fy = py - y0f, fx = pxx - x0f;
      const int iy0 = (int)y0f, ix0 = (int)x0f;
      const int iy1 = iy0 + 1,  ix1 = ix0 + 1;
      const float mm = 1.f / (1.f + expf(-hm));   // sigmoid mask folded in
      const float vy0 = (iy0 >= 0 && iy0 < HH) ? mm : 0.f;
      const float vy1 = (iy1 >= 0 && iy1 < HH) ? mm : 0.f;
      const float vx0 = (ix0 >= 0 && ix0 < WW) ? 1.f : 0.f;
      const float vx1 = (ix1 >= 0 && ix1 < WW) ? 1.f : 0.f;
      w00[k] = (1.f - fy) * (1.f - fx) * vy0 * vx0;
      w01[k] = (1.f - fy) * fx * vy0 * vx1;
      w10[k] = fy * (1.f - fx) * vy1 * vx0;
      w11[k] = fy * fx * vy1 * vx1;
      const int cy0 = imin(imax(iy0, 0), HH - 1);
      const int cy1 = imin(imax(iy1, 0), HH - 1);
      const int cx0 = imin(imax(ix0, 0), WW - 1);
      const int cx1 = imin(imax(ix1, 0), WW - 1);
      i00[k] = cy0 * WW + cx0;
      i01[k] = cy0 * WW + cx1;
      i10[k] = cy1 * WW + cx0;
      i11[k] = cy1 * WW + cx1;
    }
  }

  f32x4 acc[8];
#pragma unroll
  for (int ct = 0; ct < 8; ++ct) acc[ct] = (f32x4){0.f, 0.f, 0.f, 0.f};

  for (int cinb = 0; cinb < 4; ++cinb) {
    const float* xb = x + (size_t)(b * 128 + cinb * 32 + g * 8) * HWSZ;
#pragma unroll
    for (int tap = 0; tap < 9; ++tap) {
      // ---- gather + bilinear for my 8 cins (k = g*8+j matches wpack)
      float s[8];
#pragma unroll
      for (int j = 0; j < 8; ++j) {
        const float* xp = xb + (size_t)j * HWSZ;
        s[j] = w00[tap] * xp[i00[tap]] + w01[tap] * xp[i01[tap]] +
               w10[tap] * xp[i10[tap]] + w11[tap] * xp[i11[tap]];
      }
      short8v ah, al;
#pragma unroll
      for (int j = 0; j < 8; ++j) {
        short h, l;
        bf16split(s[j], h, l);
        ah[j] = h;
        al[j] = l;
      }
      const int ks = cinb * 9 + tap;
#pragma unroll
      for (int ct = 0; ct < 8; ++ct) {
        const size_t off = ((size_t)(ct * 36 + ks) * 64 + lane) * 8;
        short8v bh = *(const short8v*)(wh + off);
        short8v bl = *(const short8v*)(wl + off);
        acc[ct] = __builtin_amdgcn_mfma_f32_16x16x32_bf16(ah, bh, acc[ct], 0, 0, 0);
        acc[ct] = __builtin_amdgcn_mfma_f32_16x16x32_bf16(ah, bl, acc[ct], 0, 0, 0);
        acc[ct] = __builtin_amdgcn_mfma_f32_16x16x32_bf16(al, bh, acc[ct], 0, 0, 0);
      }
    }
  }

  // ---- epilogue: col = lane&15 (co), rows = (lane>>4)*4 + reg (px)
  const int co_l = lane & 15;
  const int pxw  = x0 + wv * 16 + (lane >> 4) * 4;
#pragma unroll
  for (int ct = 0; ct < 8; ++ct) {
    const int co = ct * 16 + co_l;
    const float bv = bias[co];
    float* op = out + ((size_t)(b * 128 + co) * HH + y) * WW + pxw;
    *(float4*)op = make_float4(acc[ct][0] + bv, acc[ct][1] + bv,
                               acc[ct][2] + bv, acc[ct][3] + bv);
  }
}

// ---------------------------------------------------------------------------
// Launch
// ---------------------------------------------------------------------------
extern "C" void kernel_launch(void* const* d_in, const int* in_sizes, int n_in,
                              void* d_out, int out_size, void* d_ws, size_t ws_size,
                              hipStream_t stream) {
  const float* x    = (const float*)d_in[0];
  const float* cond = (const float*)d_in[1];
  const float* flow = (const float*)d_in[2];
  const float* w1 = (const float*)d_in[3];
  const float* b1 = (const float*)d_in[4];
  const float* w2 = (const float*)d_in[5];
  const float* b2 = (const float*)d_in[6];
  const float* w3 = (const float*)d_in[7];
  const float* b3 = (const float*)d_in[8];
  const float* w4 = (const float*)d_in[9];
  const float* b4 = (const float*)d_in[10];
  const float* wd = (const float*)d_in[11];
  const float* bd = (const float*)d_in[12];
  float* out = (float*)d_out;
  float* ws  = (float*)d_ws;

  // workspace layout (floats); head aliases f2 (dead after conv3)
  float* f1    = ws;                       // 8388608
  float* f2    = f1 + 8388608;             // 8388608
  float* headb = f2;                       // aliases f2
  short* pk1h = (short*)(f2 + 8388608);    // 331776 shorts
  short* pk1l = pk1h + 331776;
  short* pk2h = pk1l + 331776;             // 147456 shorts
  short* pk2l = pk2h + 147456;
  short* pk3h = pk2l + 147456;
  short* pk3l = pk3h + 147456;
  short* pk4h = pk3l + 147456;             // 36864 shorts
  short* pk4l = pk4h + 36864;
  short* pkdh = pk4l + 36864;              // 147456 shorts
  short* pkdl = pkdh + 147456;
  // total = 16777216 + 811008 floats = 70.4 MB

  dim3 blk256(256);

  // ---- weight prepacks (tiny)
  hipLaunchKernelGGL(wpack_kernel, dim3(1296), blk256, 0, stream, w1, pk1h, pk1l, 8, 81, 261, 128);
  hipLaunchKernelGGL(wpack_kernel, dim3(576),  blk256, 0, stream, w2, pk2h, pk2l, 8, 36, 128, 128);
  hipLaunchKernelGGL(wpack_kernel, dim3(576),  blk256, 0, stream, w3, pk3h, pk3l, 8, 36, 128, 128);
  hipLaunchKernelGGL(wpack_kernel, dim3(144),  blk256, 0, stream, w4, pk4h, pk4l, 2, 36, 128, 27);
  hipLaunchKernelGGL(wpack_kernel, dim3(576),  blk256, 0, stream, wd, pkdh, pkdl, 8, 36, 128, 128);

  dim3 cgrid(1024);   // 2 x-halves * 128 y * 4 b, XCD-swizzled in-kernel
  // conv1: cond(261, CB=9) -> f1, lrelu
  hipLaunchKernelGGL(conv_mfma_kernel<8>, cgrid, blk256, 0, stream, cond, pk1h, pk1l, b1, f1, 261, 9, 128, 1);
  // conv2: f1 -> f2, lrelu
  hipLaunchKernelGGL(conv_mfma_kernel<8>, cgrid, blk256, 0, stream, f1, pk2h, pk2l, b2, f2, 128, 4, 128, 1);
  // conv3: f2 -> f1, lrelu
  hipLaunchKernelGGL(conv_mfma_kernel<8>, cgrid, blk256, 0, stream, f2, pk3h, pk3l, b3, f1, 128, 4, 128, 1);
  // conv4 (head): f1 -> headb (aliases f2, safe), no activation
  hipLaunchKernelGGL(conv_mfma_kernel<2>, cgrid, blk256, 0, stream, f1, pk4h, pk4l, b4, headb, 128, 4, 27, 0);
  // deformable conv via MFMA (LDS-free, reg-resident bilinear params)
  hipLaunchKernelGGL(deform_mfma_kernel, cgrid, blk256, 0, stream, x, headb, flow, pkdh, pkdl, bd, out);
}

// Round 10
// 961.178 us; speedup vs baseline: 2.7286x; 1.0813x over previous
//
#include <hip/hip_runtime.h>
#include <cmath>

#define HH 128
#define WW 128
#define HWSZ (HH * WW)

typedef __attribute__((ext_vector_type(8))) short short8v;
typedef __attribute__((ext_vector_type(4))) float f32x4;

static __device__ __forceinline__ int imin(int a, int b) { return a < b ? a : b; }
static __device__ __forceinline__ int imax(int a, int b) { return a > b ? a : b; }

// Split fp32 -> bf16 hi + bf16 lo (RNE both), f ~= hi + lo with residual ~2^-17|f|
static __device__ __forceinline__ void bf16split(float f, short& hi, short& lo) {
  unsigned u = __float_as_uint(f);
  unsigned rh = u + 0x7fffu + ((u >> 16) & 1u);
  hi = (short)(rh >> 16);
  float fh = __uint_as_float((rh >> 16) << 16);
  float res = f - fh;
  unsigned v = __float_as_uint(res);
  unsigned rl = v + 0x7fffu + ((v >> 16) & 1u);
  lo = (short)(rl >> 16);
}

// ---------------------------------------------------------------------------
// NCHW fp32 -> NHWC fp32, channel-padded (pad channels written as 0).
// idx order: channel-group outer, pixel inner -> coalesced reads.
// ---------------------------------------------------------------------------
__global__ void nhwc_kernel(const float* __restrict__ src, float* __restrict__ dst,
                            int C_real, int CP) {
  const int npx = 4 * HWSZ;
  int idx = blockIdx.x * 256 + threadIdx.x;
  int total = (CP / 8) * npx;
  if (idx >= total) return;
  const int pixg = idx % npx;            // b*HWSZ + pix
  const int c8   = idx / npx;
  const int b    = pixg / HWSZ;
  const int pix  = pixg % HWSZ;
  float v[8];
#pragma unroll
  for (int j = 0; j < 8; ++j) {
    const int c = c8 * 8 + j;
    v[j] = (c < C_real) ? src[((size_t)b * C_real + c) * HWSZ + pix] : 0.f;
  }
  float* dp = dst + (size_t)pixg * CP + c8 * 8;
  *(float4*)dp       = make_float4(v[0], v[1], v[2], v[3]);
  *(float4*)(dp + 4) = make_float4(v[4], v[5], v[6], v[7]);
}

// ---------------------------------------------------------------------------
// MFMA weight prepack: w[cout][cin_real][3][3] -> per-lane B-fragments.
// K order: ks = cinblk*9 + tap; within a K-step of 32: k = (lane>>4)*8 + j = cin_local.
// whi/wlo[((ct*nks + ks)*64 + lane)*8 + j] = bf16hi/lo(w[ct*16+(lane&15)][cin][tap])
// ---------------------------------------------------------------------------
__global__ void wpack_kernel(const float* __restrict__ w, short* __restrict__ whi,
                             short* __restrict__ wlo, int nct, int nks,
                             int cin_real, int cout) {
  int idx = blockIdx.x * 256 + threadIdx.x;
  int total = nct * nks * 512;
  if (idx >= total) return;
  int j    = idx & 7;
  int lane = (idx >> 3) & 63;
  int t2   = idx >> 9;
  int ks   = t2 % nks;
  int ct   = t2 / nks;
  int cinb = ks / 9, tap = ks % 9;
  int cin = cinb * 32 + (lane >> 4) * 8 + j;
  int co  = ct * 16 + (lane & 15);
  float v = 0.f;
  if (co < cout && cin < cin_real) v = w[((size_t)co * cin_real + cin) * 9 + tap];
  short hi, lo;
  bf16split(v, hi, lo);
  whi[idx] = hi;
  wlo[idx] = lo;
}

// ---------------------------------------------------------------------------
// 3x3 conv via MFMA bf16 3-product split, LDS-free, NHWC in / NHWC out.
// Block 256 = 4 waves; wave wv owns px-tile wv (16 px), lane&15 = px (A-row
// convention), and all NCT*16 couts. Per K-step (cinblk 32 x tap): A-frag is a
// direct 32B NHWC load (8 cins) split to hi/lo; B prepacked per-lane 16B.
// D: col=lane&15 (co), row=(lane>>4)*4+reg (px). No barriers at all.
// ---------------------------------------------------------------------------
template <int NCT>
__global__ __launch_bounds__(256, 2) void conv_nhwc_kernel(
    const float* __restrict__ in, const short* __restrict__ wh,
    const short* __restrict__ wl, const float* __restrict__ bias,
    float* __restrict__ out, int CP, int CB, int OP, int cout, int lrelu) {
  const int tid = threadIdx.x;
  int bid = blockIdx.x;                  // 1024 blocks, 1024%8==0
  bid = (bid & 7) * 128 + (bid >> 3);    // XCD-contiguous chunks of 128
  const int x0 = (bid & 1) * 64;
  const int y  = (bid >> 1) & 127;
  const int b  = bid >> 8;
  const int lane = tid & 63;
  const int wv = tid >> 6;
  const int m = lane & 15;
  const int g = lane >> 4;
  const int NKS = CB * 9;
  const int gx = x0 + wv * 16 + m;       // this lane's output pixel x

  f32x4 acc[NCT];
#pragma unroll
  for (int ct = 0; ct < NCT; ++ct) acc[ct] = (f32x4){0.f, 0.f, 0.f, 0.f};

  const float* inb = in + (size_t)b * HWSZ * CP;

  for (int cb = 0; cb < CB; ++cb) {
    const int cbase = cb * 32 + g * 8;
#pragma unroll
    for (int tap = 0; tap < 9; ++tap) {
      const int r = tap / 3;
      const int c = tap - r * 3;
      const int gy  = y + r - 1;
      const int gxx = gx + c - 1;
      const bool valid = ((unsigned)gy < (unsigned)HH) && ((unsigned)gxx < (unsigned)WW);
      const int cy = imin(imax(gy, 0), HH - 1);
      const int cx = imin(imax(gxx, 0), WW - 1);
      const float* ap = inb + (size_t)(cy * WW + cx) * CP + cbase;
      f32x4 a0 = *(const f32x4*)ap;
      f32x4 a1 = *(const f32x4*)(ap + 4);
      if (!valid) {
        a0 = (f32x4){0.f, 0.f, 0.f, 0.f};
        a1 = (f32x4){0.f, 0.f, 0.f, 0.f};
      }
      short8v ah, al;
#pragma unroll
      for (int j = 0; j < 4; ++j) {
        short h, l;
        bf16split(a0[j], h, l);
        ah[j] = h; al[j] = l;
        bf16split(a1[j], h, l);
        ah[j + 4] = h; al[j + 4] = l;
      }
      const int ks = cb * 9 + tap;
#pragma unroll
      for (int ct = 0; ct < NCT; ++ct) {
        const size_t off = ((size_t)(ct * NKS + ks) * 64 + lane) * 8;
        short8v bh = *(const short8v*)(wh + off);
        short8v bl = *(const short8v*)(wl + off);
        acc[ct] = __builtin_amdgcn_mfma_f32_16x16x32_bf16(ah, bh, acc[ct], 0, 0, 0);
        acc[ct] = __builtin_amdgcn_mfma_f32_16x16x32_bf16(ah, bl, acc[ct], 0, 0, 0);
        acc[ct] = __builtin_amdgcn_mfma_f32_16x16x32_bf16(al, bh, acc[ct], 0, 0, 0);
      }
    }
  }

  // ---- epilogue: NHWC out. lane col = co; rows = 4 consecutive px.
  const int co_l = lane & 15;
  const int px0  = x0 + wv * 16 + (lane >> 4) * 4;
#pragma unroll
  for (int ct = 0; ct < NCT; ++ct) {
    const int co = ct * 16 + co_l;
    if (co < cout) {
      const float bv = bias[co];
#pragma unroll
      for (int q = 0; q < 4; ++q) {
        float v = acc[ct][q] + bv;
        if (lrelu) v = (v >= 0.f) ? v : 0.1f * v;
        out[((size_t)b * HWSZ + y * WW + px0 + q) * OP + co] = v;
      }
    }
  }
}

// ---------------------------------------------------------------------------
// Modulated deformable conv 3x3 via MFMA, LDS-free, NHWC x/head inputs.
// Per lane: 9-tap bilinear params in registers; per K-step gather 4 corners x
// 8 contiguous cins (2 float4 each), combine, split, 8ct x 3 MFMA.
// Output written NCHW fp32 (reference layout).
// ---------------------------------------------------------------------------
__global__ __launch_bounds__(256, 2) void deform_nhwc_kernel(
    const float* __restrict__ xt, const float* __restrict__ headt,
    const float* __restrict__ flow, const short* __restrict__ wh,
    const short* __restrict__ wl, const float* __restrict__ bias,
    float* __restrict__ out) {
  const int tid = threadIdx.x;
  int bid = blockIdx.x;                  // 1024 blocks
  bid = (bid & 7) * 128 + (bid >> 3);    // XCD-contiguous
  const int x0 = (bid & 1) * 64;
  const int y  = (bid >> 1) & 127;
  const int b  = bid >> 8;
  const int lane = tid & 63;
  const int wv = tid >> 6;
  const int m = lane & 15;
  const int g = lane >> 4;
  const int gx = x0 + wv * 16 + m;       // this lane's pixel (A row = lane&15)

  // ---- per-tap bilinear params for pixel (y, gx); head NHWC: 27 contiguous
  int   i00[9], i01[9], i10[9], i11[9];
  float w00[9], w01[9], w10[9], w11[9];
  {
    const size_t pix = (size_t)y * WW + gx;
    const float* hb = headt + ((size_t)b * HWSZ + pix) * 32;
    const float fly = flow[((size_t)b * 2 + 1) * HWSZ + pix];   // flow[:,1] -> dy
    const float flx = flow[((size_t)b * 2 + 0) * HWSZ + pix];   // flow[:,0] -> dx
#pragma unroll
    for (int k = 0; k < 9; ++k) {
      const float hy = hb[2 * k];
      const float hx = hb[2 * k + 1];
      const float hm = hb[18 + k];
      const float dy = 3.f * tanhf(hy) + fly;
      const float dx = 3.f * tanhf(hx) + flx;
      const float py  = (float)(y - 1 + (k / 3)) + dy;
      const float pxx = (float)(gx - 1 + (k % 3)) + dx;
      const float y0f = floorf(py), x0f = floorf(pxx);
      const float fy = py - y0f, fx = pxx - x0f;
      const int iy0 = (int)y0f, ix0 = (int)x0f;
      const int iy1 = iy0 + 1,  ix1 = ix0 + 1;
      const float mm = 1.f / (1.f + expf(-hm));   // sigmoid mask folded in
      const float vy0 = (iy0 >= 0 && iy0 < HH) ? mm : 0.f;
      const float vy1 = (iy1 >= 0 && iy1 < HH) ? mm : 0.f;
      const float vx0 = (ix0 >= 0 && ix0 < WW) ? 1.f : 0.f;
      const float vx1 = (ix1 >= 0 && ix1 < WW) ? 1.f : 0.f;
      w00[k] = (1.f - fy) * (1.f - fx) * vy0 * vx0;
      w01[k] = (1.f - fy) * fx * vy0 * vx1;
      w10[k] = fy * (1.f - fx) * vy1 * vx0;
      w11[k] = fy * fx * vy1 * vx1;
      const int cy0 = imin(imax(iy0, 0), HH - 1);
      const int cy1 = imin(imax(iy1, 0), HH - 1);
      const int cx0 = imin(imax(ix0, 0), WW - 1);
      const int cx1 = imin(imax(ix1, 0), WW - 1);
      i00[k] = cy0 * WW + cx0;
      i01[k] = cy0 * WW + cx1;
      i10[k] = cy1 * WW + cx0;
      i11[k] = cy1 * WW + cx1;
    }
  }

  f32x4 acc[8];
#pragma unroll
  for (int ct = 0; ct < 8; ++ct) acc[ct] = (f32x4){0.f, 0.f, 0.f, 0.f};

  const float* xb = xt + (size_t)b * HWSZ * 128;

  for (int cinb = 0; cinb < 4; ++cinb) {
    const int cbase = cinb * 32 + g * 8;
#pragma unroll
    for (int tap = 0; tap < 9; ++tap) {
      const float* p00 = xb + (size_t)i00[tap] * 128 + cbase;
      const float* p01 = xb + (size_t)i01[tap] * 128 + cbase;
      const float* p10 = xb + (size_t)i10[tap] * 128 + cbase;
      const float* p11 = xb + (size_t)i11[tap] * 128 + cbase;
      f32x4 c00a = *(const f32x4*)p00, c00b = *(const f32x4*)(p00 + 4);
      f32x4 c01a = *(const f32x4*)p01, c01b = *(const f32x4*)(p01 + 4);
      f32x4 c10a = *(const f32x4*)p10, c10b = *(const f32x4*)(p10 + 4);
      f32x4 c11a = *(const f32x4*)p11, c11b = *(const f32x4*)(p11 + 4);
      short8v ah, al;
#pragma unroll
      for (int j = 0; j < 4; ++j) {
        float s0 = w00[tap] * c00a[j] + w01[tap] * c01a[j] +
                   w10[tap] * c10a[j] + w11[tap] * c11a[j];
        float s1 = w00[tap] * c00b[j] + w01[tap] * c01b[j] +
                   w10[tap] * c10b[j] + w11[tap] * c11b[j];
        short h, l;
        bf16split(s0, h, l);
        ah[j] = h; al[j] = l;
        bf16split(s1, h, l);
        ah[j + 4] = h; al[j + 4] = l;
      }
      const int ks = cinb * 9 + tap;
#pragma unroll
      for (int ct = 0; ct < 8; ++ct) {
        const size_t off = ((size_t)(ct * 36 + ks) * 64 + lane) * 8;
        short8v bh = *(const short8v*)(wh + off);
        short8v bl = *(const short8v*)(wl + off);
        acc[ct] = __builtin_amdgcn_mfma_f32_16x16x32_bf16(ah, bh, acc[ct], 0, 0, 0);
        acc[ct] = __builtin_amdgcn_mfma_f32_16x16x32_bf16(ah, bl, acc[ct], 0, 0, 0);
        acc[ct] = __builtin_amdgcn_mfma_f32_16x16x32_bf16(al, bh, acc[ct], 0, 0, 0);
      }
    }
  }

  // ---- epilogue: NCHW out. col = lane&15 (co), rows = (lane>>4)*4 + reg (px)
  const int co_l = lane & 15;
  const int pxw  = x0 + wv * 16 + (lane >> 4) * 4;
#pragma unroll
  for (int ct = 0; ct < 8; ++ct) {
    const int co = ct * 16 + co_l;
    const float bv = bias[co];
    float* op = out + ((size_t)(b * 128 + co) * HH + y) * WW + pxw;
    *(float4*)op = make_float4(acc[ct][0] + bv, acc[ct][1] + bv,
                               acc[ct][2] + bv, acc[ct][3] + bv);
  }
}

// ---------------------------------------------------------------------------
// Launch
// ---------------------------------------------------------------------------
extern "C" void kernel_launch(void* const* d_in, const int* in_sizes, int n_in,
                              void* d_out, int out_size, void* d_ws, size_t ws_size,
                              hipStream_t stream) {
  const float* x    = (const float*)d_in[0];
  const float* cond = (const float*)d_in[1];
  const float* flow = (const float*)d_in[2];
  const float* w1 = (const float*)d_in[3];
  const float* b1 = (const float*)d_in[4];
  const float* w2 = (const float*)d_in[5];
  const float* b2 = (const float*)d_in[6];
  const float* w3 = (const float*)d_in[7];
  const float* b3 = (const float*)d_in[8];
  const float* w4 = (const float*)d_in[9];
  const float* b4 = (const float*)d_in[10];
  const float* wd = (const float*)d_in[11];
  const float* bd = (const float*)d_in[12];
  float* out = (float*)d_out;
  float* ws  = (float*)d_ws;

  // workspace layout (floats), lifetime-aliased. Total 28,073,984 f = 112.3 MB
  // A region (18,874,368 f): cond_t [65536][288]   (dead after conv1)
  //   then: f2 [65536][128] = A[0..8388608)        (live conv2..conv3)
  //         x_t [65536][128] = A[8388608..16777216) (written after conv1; live->deform)
  //         head [65536][32] = A[0..2097152)        (written conv4 over dead f2)
  float* A  = ws;
  float* condt = A;
  float* f2    = A;
  float* headt = A;
  float* xt    = A + 8388608;
  float* f1    = ws + 18874368;            // 8,388,608 f
  short* pk1h = (short*)(ws + 27262976);   // 331,776 shorts
  short* pk1l = pk1h + 331776;
  short* pk2h = pk1l + 331776;             // 147,456 shorts
  short* pk2l = pk2h + 147456;
  short* pk3h = pk2l + 147456;
  short* pk3l = pk3h + 147456;
  short* pk4h = pk3l + 147456;             // 36,864 shorts
  short* pk4l = pk4h + 36864;
  short* pkdh = pk4l + 36864;              // 147,456 shorts
  short* pkdl = pkdh + 147456;

  dim3 blk256(256);

  // ---- transforms + weight prepacks
  hipLaunchKernelGGL(nhwc_kernel, dim3(9216), blk256, 0, stream, cond, condt, 261, 288);
  hipLaunchKernelGGL(wpack_kernel, dim3(1296), blk256, 0, stream, w1, pk1h, pk1l, 8, 81, 261, 128);
  hipLaunchKernelGGL(wpack_kernel, dim3(576),  blk256, 0, stream, w2, pk2h, pk2l, 8, 36, 128, 128);
  hipLaunchKernelGGL(wpack_kernel, dim3(576),  blk256, 0, stream, w3, pk3h, pk3l, 8, 36, 128, 128);
  hipLaunchKernelGGL(wpack_kernel, dim3(144),  blk256, 0, stream, w4, pk4h, pk4l, 2, 36, 128, 27);
  hipLaunchKernelGGL(wpack_kernel, dim3(576),  blk256, 0, stream, wd, pkdh, pkdl, 8, 36, 128, 128);

  dim3 cgrid(1024);   // 2 x-halves * 128 y * 4 b, XCD-swizzled in-kernel
  // conv1: cond_t(288, CB=9) -> f1, lrelu
  hipLaunchKernelGGL(conv_nhwc_kernel<8>, cgrid, blk256, 0, stream, condt, pk1h, pk1l, b1, f1, 288, 9, 128, 128, 1);
  // x transform (after conv1: x_t region overlapped cond_t)
  hipLaunchKernelGGL(nhwc_kernel, dim3(4096), blk256, 0, stream, x, xt, 128, 128);
  // conv2: f1 -> f2, lrelu
  hipLaunchKernelGGL(conv_nhwc_kernel<8>, cgrid, blk256, 0, stream, f1, pk2h, pk2l, b2, f2, 128, 4, 128, 128, 1);
  // conv3: f2 -> f1, lrelu
  hipLaunchKernelGGL(conv_nhwc_kernel<8>, cgrid, blk256, 0, stream, f2, pk3h, pk3l, b3, f1, 128, 4, 128, 128, 1);
  // conv4 (head): f1 -> head (32-pad NHWC, over dead f2), no activation
  hipLaunchKernelGGL(conv_nhwc_kernel<2>, cgrid, blk256, 0, stream, f1, pk4h, pk4l, b4, headt, 128, 4, 32, 27, 0);
  // deformable conv via MFMA, NHWC gathers, NCHW output
  hipLaunchKernelGGL(deform_nhwc_kernel, cgrid, blk256, 0, stream, xt, headt, flow, pkdh, pkdl, bd, out);
}